// Round 7
// baseline (111.185 us; speedup 1.0000x reference)
//
#include <hip/hip_runtime.h>
#include <hip/hip_fp16.h>

#define B 32
#define O 64
#define M 128
#define H 4
#define E 64
#define LOG2E 1.44269504088896341f

#if __has_builtin(__builtin_amdgcn_exp2f)
#define EXP2F(x) __builtin_amdgcn_exp2f(x)
#else
#define EXP2F(x) __exp2f(x)
#endif

typedef _Float16 f16x2 __attribute__((ext_vector_type(2)));

__device__ __forceinline__ float rl(float v, int lane) {
    return __uint_as_float(__builtin_amdgcn_readlane(__float_as_uint(v), lane));
}
__device__ __forceinline__ unsigned rlu(unsigned v, int lane) {
    return (unsigned)__builtin_amdgcn_readlane((int)v, lane);
}
__device__ __forceinline__ unsigned pk2h(float a, float b) {
    return (unsigned)__half_as_ushort(__float2half_rn(a)) |
           ((unsigned)__half_as_ushort(__float2half_rn(b)) << 16);
}
__device__ __forceinline__ _Float16 rcph(_Float16 x) {
#if __has_builtin(__builtin_amdgcn_rcph)
    return __builtin_amdgcn_rcph(x);
#else
    return (_Float16)1.0f / x;
#endif
}

// ============ prep: blocks 0..31 convert ctx(->T,fp16) + mem(fp16);
//              blocks 32..543: q_pk = pack2(query@W_ch + b_ch), 4 rows/block ====
__global__ __launch_bounds__(256) void prep_kernel(
    const float* __restrict__ query, const float* __restrict__ context,
    const float* __restrict__ memory, const float* __restrict__ W_ch,
    const float* __restrict__ b_ch,
    __half* __restrict__ ctx_T, __half* __restrict__ mem_h, unsigned* __restrict__ q_pk)
{
    __shared__ float s[128 * 68];          // conv path: ctx staged stride-68
    const int t = threadIdx.x, blk = blockIdx.x;

    if (blk < 32) {
        const int b = blk;
        const float* ctx = context + b * (M * E);
        #pragma unroll
        for (int i = 0; i < 8; ++i) {       // stage ctx coalesced
            int idx = i * 1024 + t * 4;
            float4 v = *(const float4*)(ctx + idx);
            int m = idx >> 6, e = idx & 63;
            *(float4*)(&s[m * 68 + e]) = v;
        }
        // memory -> fp16 (no transpose), coalesced 8B stores
        {
            const float* mem = memory + b * (M * E);
            __half* mh = mem_h + (size_t)b * (M * E);
            #pragma unroll
            for (int i = 0; i < 8; ++i) {
                int idx = i * 1024 + t * 4;
                float4 v = *(const float4*)(mem + idx);
                *(uint2*)(mh + idx) = make_uint2(pk2h(v.x, v.y), pk2h(v.z, v.w));
            }
        }
        __syncthreads();
        // transpose out: thread -> (e = t>>2, m-block = (t&3)*32), 64B store
        {
            int e = t >> 2, mb = (t & 3) * 32;
            uint4 o[4];
            #pragma unroll
            for (int qd = 0; qd < 4; ++qd) {
                unsigned u[4];
                #pragma unroll
                for (int k = 0; k < 4; ++k) {
                    int m0 = mb + qd * 8 + 2 * k;
                    u[k] = pk2h(s[m0 * 68 + e], s[(m0 + 1) * 68 + e]);
                }
                o[qd] = make_uint4(u[0], u[1], u[2], u[3]);
            }
            uint4* dst = (uint4*)(ctx_T + (size_t)b * (E * M) + e * M + mb);
            dst[0] = o[0]; dst[1] = o[1]; dst[2] = o[2]; dst[3] = o[3];
        }
    } else {
        const int r0 = (blk - 32) * 4;      // 4 query rows (bo indices)
        // stage 4x64 query transposed into s[k*4+r]
        s[t] = query[(r0 + (t & 3)) * 64 + (t >> 2)];
        __syncthreads();
        float bc = b_ch[t];
        float a0 = bc, a1 = bc, a2 = bc, a3 = bc;
        #pragma unroll 8
        for (int k = 0; k < 64; ++k) {
            float4 qv = *(const float4*)(&s[k * 4]);   // uniform ds_read_b128
            float wv = W_ch[k * 256 + t];
            a0 = fmaf(qv.x, wv, a0);
            a1 = fmaf(qv.y, wv, a1);
            a2 = fmaf(qv.z, wv, a2);
            a3 = fmaf(qv.w, wv, a3);
        }
        unsigned* qa = q_pk + (size_t)r0 * 256 + t;
        qa[0] = pk2h(a0, a0); qa[256] = pk2h(a1, a1);
        qa[512] = pk2h(a2, a2); qa[768] = pk2h(a3, a3);
    }
}

// ============ main: packed-fp16 Pade[7/6] tanh, 2 trans/iter ====
__global__ __launch_bounds__(256) void attn_main(
    const __half* __restrict__ ctx_T, const __half* __restrict__ mem_h,
    const unsigned* __restrict__ q_pk, const float* __restrict__ w_logit,
    const float* __restrict__ b_logit, const float* __restrict__ temp,
    __half* __restrict__ heads_h)
{
    __shared__ __half s_ctx[E * M];      // [e][m] fp16 raw, 16 KB
    __shared__ float  s_prob[M * H];     // [m][h]  2 KB
    __shared__ float  s_part[H * 4 * E]; // [h][wave][e] 4 KB

    const int t = threadIdx.x, lane = t & 63, w = t >> 6;
    const int bo = blockIdx.x, b = bo >> 6;

    // stage ctx_T[b] (16 KB, dwordx4)
    {
        const uint4* g1 = (const uint4*)(ctx_T + (size_t)b * (E * M));
        uint4* l1 = (uint4*)s_ctx;
        #pragma unroll
        for (int p = 0; p < 4; ++p)
            l1[p * 256 + t] = g1[p * 256 + t];
    }
    const unsigned qu = q_pk[bo * 256 + t];   // packed (q,q) fp16, c = t = w*64+lane
    const float    wl = w_logit[lane];        // f32 w per lane
    const float bl  = b_logit[0];
    const float lsc = LOG2E / temp[0];
    __syncthreads();

    // tanh+logit: wave w = head, lane covers m = 2*lane, 2*lane+1 (f16x2 halves)
    // tanh(x) ~= x*(10395+1260u+21u^2)/(10395+4725u+210u^2+u^3), u=x^2, |x|<=5
    // coefficients /16 to stay in fp16 range (scale cancels in the ratio)
    const f16x2 A0 = {(_Float16)649.6875f, (_Float16)649.6875f};
    const f16x2 A1 = {(_Float16)78.75f,    (_Float16)78.75f};
    const f16x2 A2 = {(_Float16)1.3125f,   (_Float16)1.3125f};
    const f16x2 B1 = {(_Float16)295.3125f, (_Float16)295.3125f};
    const f16x2 B2 = {(_Float16)13.125f,   (_Float16)13.125f};
    const f16x2 B3 = {(_Float16)0.0625f,   (_Float16)0.0625f};
    const f16x2 P5 = {(_Float16)5.0f,      (_Float16)5.0f};
    const f16x2 N5 = {(_Float16)-5.0f,     (_Float16)-5.0f};
    float acc0 = 0.f, acc1 = 0.f;
    const f16x2* c2p = (const f16x2*)s_ctx;
    #pragma unroll 8
    for (int e = 0; e < 64; ++e) {
        f16x2 c2 = c2p[e * 64 + lane];
        union { unsigned u; f16x2 h; } qb; qb.u = rlu(qu, e);
        float we = rl(wl, e);
        f16x2 x2 = c2 + qb.h;
        x2 = __builtin_elementwise_max(x2, N5);
        x2 = __builtin_elementwise_min(x2, P5);
        f16x2 u2 = x2 * x2;
        f16x2 n  = u2 * A2 + A1;  n = u2 * n + A0;
        f16x2 d  = u2 * B3 + B2;  d = u2 * d + B1;  d = u2 * d + A0;
        f16x2 xn = x2 * n;
        _Float16 t0 = xn.x * rcph(d.x);
        _Float16 t1 = xn.y * rcph(d.y);
        acc0 = fmaf((float)t0, we, acc0);   // v_fma_mix candidates
        acc1 = fmaf((float)t1, we, acc1);
    }

    // softmax over m (wave butterfly); logits scaled by log2e -> raw v_exp
    float l0 = fmaf(acc0, lsc, bl * lsc);
    float l1 = fmaf(acc1, lsc, bl * lsc);
    float mx = fmaxf(l0, l1);
    #pragma unroll
    for (int sft = 1; sft < 64; sft <<= 1) mx = fmaxf(mx, __shfl_xor(mx, sft));
    float e0 = EXP2F(l0 - mx);
    float e1 = EXP2F(l1 - mx);
    float sum = e0 + e1;
    #pragma unroll
    for (int sft = 1; sft < 64; sft <<= 1) sum += __shfl_xor(sum, sft);
    float rs = __builtin_amdgcn_rcpf(sum);
    s_prob[(2 * lane) * H + w]     = e0 * rs;
    s_prob[(2 * lane + 1) * H + w] = e1 * rs;
    __syncthreads();

    // cooperative heads: wave w covers m in [32w,32w+32), all 4 heads; lane = e
    float h0 = 0.f, h1 = 0.f, h2 = 0.f, h3 = 0.f;
    {
        const __half* mem = mem_h + (size_t)b * (M * E) + lane;
        #pragma unroll 8
        for (int i = 0; i < 32; ++i) {
            int m = 32 * w + i;
            float4 p = *(const float4*)(&s_prob[m * 4]);    // uniform b128
            float mv = __half2float(mem[m * 64]);
            h0 = fmaf(p.x, mv, h0);
            h1 = fmaf(p.y, mv, h1);
            h2 = fmaf(p.z, mv, h2);
            h3 = fmaf(p.w, mv, h3);
        }
    }
    s_part[0 * 256 + w * 64 + lane] = h0;
    s_part[1 * 256 + w * 64 + lane] = h1;
    s_part[2 * 256 + w * 64 + lane] = h2;
    s_part[3 * 256 + w * 64 + lane] = h3;
    __syncthreads();
    float hv = s_part[w * 256 + lane] + s_part[w * 256 + 64 + lane]
             + s_part[w * 256 + 128 + lane] + s_part[w * 256 + 192 + lane];
    hv = (hv > 0.f) ? hv : 0.01f * hv;
    heads_h[(size_t)bo * 256 + t] = __float2half_rn(hv);
}

// ============ post: out = heads @ W_rh + b_rh ; 4 rows/block, 512 blocks ====
__global__ __launch_bounds__(256) void post_kernel(
    const __half* __restrict__ heads_h, const float* __restrict__ W_rh,
    const float* __restrict__ b_rh, float* __restrict__ out)
{
    __shared__ __half s_h[4 * 256];     // 2KB
    const int t = threadIdx.x, lane = t & 63, r = t >> 6;   // wave = row
    const int r0 = blockIdx.x * 4;
    ((uint4*)s_h)[t & 127] = ((const uint4*)(heads_h + (size_t)r0 * 256))[t & 127];
    __syncthreads();
    const __half2* hr = (const __half2*)(s_h + r * 256);
    const float* Wp = W_rh + lane;
    float acc = 0.f;
    #pragma unroll 8
    for (int jp = 0; jp < 128; ++jp) {
        float2 hh = __half22float2(hr[jp]);    // uniform per wave
        acc = fmaf(hh.x, Wp[(2 * jp) * 64], acc);
        acc = fmaf(hh.y, Wp[(2 * jp + 1) * 64], acc);
    }
    out[(size_t)(r0 + r) * 64 + lane] = acc + b_rh[lane];
}

extern "C" void kernel_launch(void* const* d_in, const int* in_sizes, int n_in,
                              void* d_out, int out_size, void* d_ws, size_t ws_size,
                              hipStream_t stream) {
    const float* query   = (const float*)d_in[0];
    const float* context = (const float*)d_in[1];
    const float* memory  = (const float*)d_in[2];
    const float* W_ch    = (const float*)d_in[3];
    const float* b_ch    = (const float*)d_in[4];
    const float* w_logit = (const float*)d_in[5];
    const float* b_logit = (const float*)d_in[6];
    const float* W_rh    = (const float*)d_in[7];
    const float* b_rh    = (const float*)d_in[8];
    const float* temp    = (const float*)d_in[9];
    float* out = (float*)d_out;

    // workspace carve: ctx_T 512K | mem_h 512K | q_pk 2M | heads_h 1M
    __half*   ctx_T   = (__half*)d_ws;
    __half*   mem_h   = ctx_T + (size_t)B * E * M;
    unsigned* q_pk    = (unsigned*)(mem_h + (size_t)B * M * E);
    __half*   heads_h = (__half*)(q_pk + (size_t)B * O * 256);

    prep_kernel<<<544, 256, 0, stream>>>(query, context, memory, W_ch, b_ch,
                                         ctx_T, mem_h, q_pk);
    attn_main<<<B * O, 256, 0, stream>>>(ctx_T, mem_h, q_pk, w_logit,
                                         b_logit, temp, heads_h);
    post_kernel<<<512, 256, 0, stream>>>(heads_h, W_rh, b_rh, out);
}

// Round 8
// 101.978 us; speedup vs baseline: 1.0903x; 1.0903x over previous
//
#include <hip/hip_runtime.h>
#include <hip/hip_fp16.h>

#define B 32
#define O 64
#define M 128
#define H 4
#define E 64
#define SC 2.88539008177792681f     // 2*log2(e): tanh(x) = 1 - 2/(1+exp2(SC*x))
#define LOG2E 1.44269504088896341f

#if __has_builtin(__builtin_amdgcn_exp2f)
#define EXP2F(x) __builtin_amdgcn_exp2f(x)
#else
#define EXP2F(x) __exp2f(x)
#endif

__device__ __forceinline__ float rl(float v, int lane) {
    return __uint_as_float(__builtin_amdgcn_readlane(__float_as_uint(v), lane));
}
__device__ __forceinline__ unsigned pk2h(float a, float b) {
    return (unsigned)__half_as_ushort(__float2half_rn(a)) |
           ((unsigned)__half_as_ushort(__float2half_rn(b)) << 16);
}

// ============ prep: blocks 0..31: ctx -> Ec = exp2(SC*c), transposed f32;
//              mem -> fp16. blocks 32..543: q -> Eq = exp2(SC*(q@W_ch+b)), f32 ====
__global__ __launch_bounds__(256) void prep_kernel(
    const float* __restrict__ query, const float* __restrict__ context,
    const float* __restrict__ memory, const float* __restrict__ W_ch,
    const float* __restrict__ b_ch,
    float* __restrict__ ctx_E, __half* __restrict__ mem_h, float* __restrict__ q_E)
{
    __shared__ float s[128 * 68];          // ctx staged stride-68
    const int t = threadIdx.x, blk = blockIdx.x;

    if (blk < 32) {
        const int b = blk;
        const float* ctx = context + b * (M * E);
        #pragma unroll
        for (int i = 0; i < 8; ++i) {       // stage ctx coalesced
            int idx = i * 1024 + t * 4;
            float4 v = *(const float4*)(ctx + idx);
            int m = idx >> 6, e = idx & 63;
            *(float4*)(&s[m * 68 + e]) = v;
        }
        // memory -> fp16 (no transpose), coalesced 8B stores
        {
            const float* mem = memory + b * (M * E);
            __half* mh = mem_h + (size_t)b * (M * E);
            #pragma unroll
            for (int i = 0; i < 8; ++i) {
                int idx = i * 1024 + t * 4;
                float4 v = *(const float4*)(mem + idx);
                *(uint2*)(mh + idx) = make_uint2(pk2h(v.x, v.y), pk2h(v.z, v.w));
            }
        }
        __syncthreads();
        // transpose out: thread -> (e = t>>2, m-block = (t&3)*32), f32 exp2
        {
            int e = t >> 2, mb = (t & 3) * 32;
            float4* dst = (float4*)(ctx_E + (size_t)b * (E * M) + e * M + mb);
            #pragma unroll
            for (int i = 0; i < 8; ++i) {
                float4 v;
                v.x = EXP2F(SC * s[(mb + 4 * i + 0) * 68 + e]);
                v.y = EXP2F(SC * s[(mb + 4 * i + 1) * 68 + e]);
                v.z = EXP2F(SC * s[(mb + 4 * i + 2) * 68 + e]);
                v.w = EXP2F(SC * s[(mb + 4 * i + 3) * 68 + e]);
                dst[i] = v;
            }
        }
    } else {
        const int r0 = (blk - 32) * 4;      // 4 query rows (bo indices)
        // stage 4x64 query transposed into s[k*4+r]
        s[t] = query[(r0 + (t & 3)) * 64 + (t >> 2)];
        __syncthreads();
        float bc = b_ch[t];
        float a0 = bc, a1 = bc, a2 = bc, a3 = bc;
        #pragma unroll 8
        for (int k = 0; k < 64; ++k) {
            float4 qv = *(const float4*)(&s[k * 4]);   // uniform ds_read_b128
            float wv = W_ch[k * 256 + t];
            a0 = fmaf(qv.x, wv, a0);
            a1 = fmaf(qv.y, wv, a1);
            a2 = fmaf(qv.z, wv, a2);
            a3 = fmaf(qv.w, wv, a3);
        }
        float* qa = q_E + (size_t)r0 * 256 + t;
        qa[0]   = EXP2F(SC * a0);
        qa[256] = EXP2F(SC * a1);
        qa[512] = EXP2F(SC * a2);
        qa[768] = EXP2F(SC * a3);
    }
}

// ============ main: zero-exp tanh via Ec*Eq + batched rcp (1 trans / 2 elems) ====
__global__ __launch_bounds__(256) void attn_main(
    const float* __restrict__ ctx_E, const __half* __restrict__ mem_h,
    const float* __restrict__ q_E, const float* __restrict__ w_logit,
    const float* __restrict__ b_logit, const float* __restrict__ temp,
    __half* __restrict__ heads_h)
{
    __shared__ float s_E[E * M];         // [e][m] Ec f32, 32 KB
    __shared__ float s_prob[M * H];      // [m][h]  2 KB
    __shared__ float s_part[H * 4 * E];  // [h][wave][e] 4 KB

    const int t = threadIdx.x, lane = t & 63, w = t >> 6;
    const int bo = blockIdx.x, b = bo >> 6;

    // stage ctx_E[b] (32 KB, dwordx4)
    {
        const uint4* g1 = (const uint4*)(ctx_E + (size_t)b * (E * M));
        uint4* l1 = (uint4*)s_E;
        #pragma unroll
        for (int p = 0; p < 8; ++p)
            l1[p * 256 + t] = g1[p * 256 + t];
    }
    const float qE = q_E[bo * 256 + t];   // exp2(SC*q), c = t = w*64+lane
    const float wl = w_logit[lane];
    float sumw = wl;
    #pragma unroll
    for (int sft = 1; sft < 64; sft <<= 1) sumw += __shfl_xor(sumw, sft);
    const float bl  = b_logit[0];
    const float lsc = LOG2E / temp[0];
    const float base = (sumw + bl) * lsc;   // logit = sumw - 2*acc + bl
    const float lsc2 = -2.0f * lsc;
    __syncthreads();

    // tanh+logit: wave w = head, lane covers m = 2*lane, 2*lane+1.
    // tanh(c+q) = 1 - 2/(1 + Ec*Eq);  batched rcp: r = rcp(a0*a1),
    // 1/a0 = a1*r, 1/a1 = a0*r  ->  1 trans per 2 elements.
    float acc0 = 0.f, acc1 = 0.f;
    const float2* Ep = (const float2*)s_E;
    #pragma unroll 8
    for (int e = 0; e < 64; ++e) {
        float2 Ec = Ep[e * 64 + lane];
        float Eq = rl(qE, e);
        float we = rl(wl, e);
        float a0 = fmaf(Ec.x, Eq, 1.0f);
        float a1 = fmaf(Ec.y, Eq, 1.0f);
        float r  = __builtin_amdgcn_rcpf(a0 * a1);
        acc0 = fmaf(we, a1 * r, acc0);   // we/(1+P0)
        acc1 = fmaf(we, a0 * r, acc1);   // we/(1+P1)
    }

    // softmax over m (wave butterfly); logits scaled by log2e -> raw v_exp
    float l0 = fmaf(lsc2, acc0, base);
    float l1 = fmaf(lsc2, acc1, base);
    float mx = fmaxf(l0, l1);
    #pragma unroll
    for (int sft = 1; sft < 64; sft <<= 1) mx = fmaxf(mx, __shfl_xor(mx, sft));
    float e0 = EXP2F(l0 - mx);
    float e1 = EXP2F(l1 - mx);
    float sum = e0 + e1;
    #pragma unroll
    for (int sft = 1; sft < 64; sft <<= 1) sum += __shfl_xor(sum, sft);
    float rs = __builtin_amdgcn_rcpf(sum);
    s_prob[(2 * lane) * H + w]     = e0 * rs;
    s_prob[(2 * lane + 1) * H + w] = e1 * rs;
    __syncthreads();

    // cooperative heads: wave w covers m in [32w,32w+32), all 4 heads; lane = e
    float h0 = 0.f, h1 = 0.f, h2 = 0.f, h3 = 0.f;
    {
        const __half* mem = mem_h + (size_t)b * (M * E) + lane;
        #pragma unroll 8
        for (int i = 0; i < 32; ++i) {
            int m = 32 * w + i;
            float4 p = *(const float4*)(&s_prob[m * 4]);    // uniform b128
            float mv = __half2float(mem[m * 64]);
            h0 = fmaf(p.x, mv, h0);
            h1 = fmaf(p.y, mv, h1);
            h2 = fmaf(p.z, mv, h2);
            h3 = fmaf(p.w, mv, h3);
        }
    }
    s_part[0 * 256 + w * 64 + lane] = h0;
    s_part[1 * 256 + w * 64 + lane] = h1;
    s_part[2 * 256 + w * 64 + lane] = h2;
    s_part[3 * 256 + w * 64 + lane] = h3;
    __syncthreads();
    float hv = s_part[w * 256 + lane] + s_part[w * 256 + 64 + lane]
             + s_part[w * 256 + 128 + lane] + s_part[w * 256 + 192 + lane];
    hv = (hv > 0.f) ? hv : 0.01f * hv;
    heads_h[(size_t)bo * 256 + t] = __float2half_rn(hv);
}

// ============ post: out = heads @ W_rh + b_rh ; 4 rows/block, 512 blocks ====
__global__ __launch_bounds__(256) void post_kernel(
    const __half* __restrict__ heads_h, const float* __restrict__ W_rh,
    const float* __restrict__ b_rh, float* __restrict__ out)
{
    __shared__ __half s_h[4 * 256];     // 2KB
    const int t = threadIdx.x, lane = t & 63, r = t >> 6;   // wave = row
    const int r0 = blockIdx.x * 4;
    ((uint4*)s_h)[t & 127] = ((const uint4*)(heads_h + (size_t)r0 * 256))[t & 127];
    __syncthreads();
    const __half2* hr = (const __half2*)(s_h + r * 256);
    const float* Wp = W_rh + lane;
    float acc = 0.f;
    #pragma unroll 8
    for (int jp = 0; jp < 128; ++jp) {
        float2 hh = __half22float2(hr[jp]);    // uniform per wave
        acc = fmaf(hh.x, Wp[(2 * jp) * 64], acc);
        acc = fmaf(hh.y, Wp[(2 * jp + 1) * 64], acc);
    }
    out[(size_t)(r0 + r) * 64 + lane] = acc + b_rh[lane];
}

extern "C" void kernel_launch(void* const* d_in, const int* in_sizes, int n_in,
                              void* d_out, int out_size, void* d_ws, size_t ws_size,
                              hipStream_t stream) {
    const float* query   = (const float*)d_in[0];
    const float* context = (const float*)d_in[1];
    const float* memory  = (const float*)d_in[2];
    const float* W_ch    = (const float*)d_in[3];
    const float* b_ch    = (const float*)d_in[4];
    const float* w_logit = (const float*)d_in[5];
    const float* b_logit = (const float*)d_in[6];
    const float* W_rh    = (const float*)d_in[7];
    const float* b_rh    = (const float*)d_in[8];
    const float* temp    = (const float*)d_in[9];
    float* out = (float*)d_out;

    // workspace carve: ctx_E 1M (f32) | mem_h 512K | q_E 2M | heads_h 1M
    float*  ctx_E   = (float*)d_ws;
    __half* mem_h   = (__half*)(ctx_E + (size_t)B * E * M);
    float*  q_E     = (float*)(mem_h + (size_t)B * M * E);
    __half* heads_h = (__half*)(q_E + (size_t)B * O * 256);

    prep_kernel<<<544, 256, 0, stream>>>(query, context, memory, W_ch, b_ch,
                                         ctx_E, mem_h, q_E);
    attn_main<<<B * O, 256, 0, stream>>>(ctx_E, mem_h, q_E, w_logit,
                                         b_logit, temp, heads_h);
    post_kernel<<<512, 256, 0, stream>>>(heads_h, W_rh, b_rh, out);
}

// Round 9
// 101.412 us; speedup vs baseline: 1.0964x; 1.0056x over previous
//
#include <hip/hip_runtime.h>
#include <hip/hip_fp16.h>

#define B 32
#define O 64
#define M 128
#define H 4
#define E 64
#define SC 2.88539008177792681f     // 2*log2(e): tanh(x) = 1 - 2/(1+exp2(SC*x))
#define LOG2E 1.44269504088896341f

#if __has_builtin(__builtin_amdgcn_exp2f)
#define EXP2F(x) __builtin_amdgcn_exp2f(x)
#else
#define EXP2F(x) __exp2f(x)
#endif

__device__ __forceinline__ unsigned pk2h(float a, float b) {
    return (unsigned)__half_as_ushort(__float2half_rn(a)) |
           ((unsigned)__half_as_ushort(__float2half_rn(b)) << 16);
}

// ============ prep: blocks 0..31: ctx -> Ec = exp2(SC*c), transposed f32;
//              mem -> fp16. blocks 32..543: q -> Eq = exp2(SC*(q@W_ch+b)), f32 ====
__global__ __launch_bounds__(256) void prep_kernel(
    const float* __restrict__ query, const float* __restrict__ context,
    const float* __restrict__ memory, const float* __restrict__ W_ch,
    const float* __restrict__ b_ch,
    float* __restrict__ ctx_E, __half* __restrict__ mem_h, float* __restrict__ q_E)
{
    __shared__ float s[128 * 68];          // ctx staged stride-68
    const int t = threadIdx.x, blk = blockIdx.x;

    if (blk < 32) {
        const int b = blk;
        const float* ctx = context + b * (M * E);
        #pragma unroll
        for (int i = 0; i < 8; ++i) {       // stage ctx coalesced
            int idx = i * 1024 + t * 4;
            float4 v = *(const float4*)(ctx + idx);
            int m = idx >> 6, e = idx & 63;
            *(float4*)(&s[m * 68 + e]) = v;
        }
        // memory -> fp16 (no transpose), coalesced 8B stores
        {
            const float* mem = memory + b * (M * E);
            __half* mh = mem_h + (size_t)b * (M * E);
            #pragma unroll
            for (int i = 0; i < 8; ++i) {
                int idx = i * 1024 + t * 4;
                float4 v = *(const float4*)(mem + idx);
                *(uint2*)(mh + idx) = make_uint2(pk2h(v.x, v.y), pk2h(v.z, v.w));
            }
        }
        __syncthreads();
        // transpose out: thread -> (e = t>>2, m-block = (t&3)*32), f32 exp2
        {
            int e = t >> 2, mb = (t & 3) * 32;
            float4* dst = (float4*)(ctx_E + (size_t)b * (E * M) + e * M + mb);
            #pragma unroll
            for (int i = 0; i < 8; ++i) {
                float4 v;
                v.x = EXP2F(SC * s[(mb + 4 * i + 0) * 68 + e]);
                v.y = EXP2F(SC * s[(mb + 4 * i + 1) * 68 + e]);
                v.z = EXP2F(SC * s[(mb + 4 * i + 2) * 68 + e]);
                v.w = EXP2F(SC * s[(mb + 4 * i + 3) * 68 + e]);
                dst[i] = v;
            }
        }
    } else {
        const int r0 = (blk - 32) * 4;      // 4 query rows (bo indices)
        // stage 4x64 query transposed into s[k*4+r]
        s[t] = query[(r0 + (t & 3)) * 64 + (t >> 2)];
        __syncthreads();
        float bc = b_ch[t];
        float a0 = bc, a1 = bc, a2 = bc, a3 = bc;
        #pragma unroll 8
        for (int k = 0; k < 64; ++k) {
            float4 qv = *(const float4*)(&s[k * 4]);   // uniform ds_read_b128
            float wv = W_ch[k * 256 + t];
            a0 = fmaf(qv.x, wv, a0);
            a1 = fmaf(qv.y, wv, a1);
            a2 = fmaf(qv.z, wv, a2);
            a3 = fmaf(qv.w, wv, a3);
        }
        float* qa = q_E + (size_t)r0 * 256 + t;
        qa[0]   = EXP2F(SC * a0);
        qa[256] = EXP2F(SC * a1);
        qa[512] = EXP2F(SC * a2);
        qa[768] = EXP2F(SC * a3);
    }
}

// ============ main: zero-exp tanh; q/w broadcast via UNIFORM LDS reads
//              (no v_readlane in hot loop -> no VALU->SGPR hazard stalls) ====
__global__ __launch_bounds__(256) void attn_main(
    const float* __restrict__ ctx_E, const __half* __restrict__ mem_h,
    const float* __restrict__ q_E, const float* __restrict__ w_logit,
    const float* __restrict__ b_logit, const float* __restrict__ temp,
    __half* __restrict__ heads_h)
{
    __shared__ float  s_E[E * M];         // [e][m] Ec f32, 32 KB
    __shared__ float2 s_qw[H * E];        // (qE, we) pairs per head, 2 KB
    __shared__ float  s_prob[M * H];      // [m][h]  2 KB
    __shared__ float  s_part[H * 4 * E];  // [h][wave][e] 4 KB

    const int t = threadIdx.x, lane = t & 63, w = t >> 6;
    const int bo = blockIdx.x, b = bo >> 6;

    // stage ctx_E[b] (32 KB, dwordx4) + qw pairs
    {
        const uint4* g1 = (const uint4*)(ctx_E + (size_t)b * (E * M));
        uint4* l1 = (uint4*)s_E;
        #pragma unroll
        for (int p = 0; p < 8; ++p)
            l1[p * 256 + t] = g1[p * 256 + t];
    }
    const float wl = w_logit[lane];
    s_qw[t] = make_float2(q_E[bo * 256 + t], wl);   // [w][e] pair
    float sumw = wl;
    #pragma unroll
    for (int sft = 1; sft < 64; sft <<= 1) sumw += __shfl_xor(sumw, sft);
    const float bl  = b_logit[0];
    const float lsc = LOG2E / temp[0];
    const float base = (sumw + bl) * lsc;   // logit = sumw - 2*acc + bl
    const float lsc2 = -2.0f * lsc;
    __syncthreads();

    // tanh+logit: wave w = head, lane covers m = 2*lane, 2*lane+1.
    // tanh(c+q) = 1 - 2/(1 + Ec*Eq); batched rcp across the 2 m's.
    // q,w come from wave-uniform ds_read_b64 (broadcast, free) - no readlane.
    float acc0 = 0.f, acc1 = 0.f;
    const float2* Ep  = (const float2*)s_E;
    const float2* qwp = (const float2*)&s_qw[w * 64];
    #pragma unroll 8
    for (int e = 0; e < 64; ++e) {
        float2 Ec = Ep[e * 64 + lane];     // varying ds_read_b64, 2-way (free)
        float2 qw = qwp[e];                // uniform ds_read_b64 (broadcast)
        float a0 = fmaf(Ec.x, qw.x, 1.0f);
        float a1 = fmaf(Ec.y, qw.x, 1.0f);
        float r  = __builtin_amdgcn_rcpf(a0 * a1);
        float wr = qw.y * r;
        acc0 = fmaf(wr, a1, acc0);   // we/(1+P0)
        acc1 = fmaf(wr, a0, acc1);   // we/(1+P1)
    }

    // softmax over m (wave butterfly); logits scaled by log2e -> raw v_exp
    float l0 = fmaf(lsc2, acc0, base);
    float l1 = fmaf(lsc2, acc1, base);
    float mx = fmaxf(l0, l1);
    #pragma unroll
    for (int sft = 1; sft < 64; sft <<= 1) mx = fmaxf(mx, __shfl_xor(mx, sft));
    float e0 = EXP2F(l0 - mx);
    float e1 = EXP2F(l1 - mx);
    float sum = e0 + e1;
    #pragma unroll
    for (int sft = 1; sft < 64; sft <<= 1) sum += __shfl_xor(sum, sft);
    float rs = __builtin_amdgcn_rcpf(sum);
    s_prob[(2 * lane) * H + w]     = e0 * rs;
    s_prob[(2 * lane + 1) * H + w] = e1 * rs;
    __syncthreads();

    // cooperative heads: wave w covers m in [32w,32w+32), all 4 heads; lane = e
    float h0 = 0.f, h1 = 0.f, h2 = 0.f, h3 = 0.f;
    {
        const __half* mem = mem_h + (size_t)b * (M * E) + lane;
        #pragma unroll 8
        for (int i = 0; i < 32; ++i) {
            int m = 32 * w + i;
            float4 p = *(const float4*)(&s_prob[m * 4]);    // uniform b128
            float mv = __half2float(mem[m * 64]);
            h0 = fmaf(p.x, mv, h0);
            h1 = fmaf(p.y, mv, h1);
            h2 = fmaf(p.z, mv, h2);
            h3 = fmaf(p.w, mv, h3);
        }
    }
    s_part[0 * 256 + w * 64 + lane] = h0;
    s_part[1 * 256 + w * 64 + lane] = h1;
    s_part[2 * 256 + w * 64 + lane] = h2;
    s_part[3 * 256 + w * 64 + lane] = h3;
    __syncthreads();
    float hv = s_part[w * 256 + lane] + s_part[w * 256 + 64 + lane]
             + s_part[w * 256 + 128 + lane] + s_part[w * 256 + 192 + lane];
    hv = (hv > 0.f) ? hv : 0.01f * hv;
    heads_h[(size_t)bo * 256 + t] = __float2half_rn(hv);
}

// ============ post: out = heads @ W_rh + b_rh ; 4 rows/block, 512 blocks ====
__global__ __launch_bounds__(256) void post_kernel(
    const __half* __restrict__ heads_h, const float* __restrict__ W_rh,
    const float* __restrict__ b_rh, float* __restrict__ out)
{
    __shared__ __half s_h[4 * 256];     // 2KB
    const int t = threadIdx.x, lane = t & 63, r = t >> 6;   // wave = row
    const int r0 = blockIdx.x * 4;
    ((uint4*)s_h)[t & 127] = ((const uint4*)(heads_h + (size_t)r0 * 256))[t & 127];
    __syncthreads();
    const __half2* hr = (const __half2*)(s_h + r * 256);
    const float* Wp = W_rh + lane;
    float acc = 0.f;
    #pragma unroll 8
    for (int jp = 0; jp < 128; ++jp) {
        float2 hh = __half22float2(hr[jp]);    // uniform per wave
        acc = fmaf(hh.x, Wp[(2 * jp) * 64], acc);
        acc = fmaf(hh.y, Wp[(2 * jp + 1) * 64], acc);
    }
    out[(size_t)(r0 + r) * 64 + lane] = acc + b_rh[lane];
}

extern "C" void kernel_launch(void* const* d_in, const int* in_sizes, int n_in,
                              void* d_out, int out_size, void* d_ws, size_t ws_size,
                              hipStream_t stream) {
    const float* query   = (const float*)d_in[0];
    const float* context = (const float*)d_in[1];
    const float* memory  = (const float*)d_in[2];
    const float* W_ch    = (const float*)d_in[3];
    const float* b_ch    = (const float*)d_in[4];
    const float* w_logit = (const float*)d_in[5];
    const float* b_logit = (const float*)d_in[6];
    const float* W_rh    = (const float*)d_in[7];
    const float* b_rh    = (const float*)d_in[8];
    const float* temp    = (const float*)d_in[9];
    float* out = (float*)d_out;

    // workspace carve: ctx_E 1M (f32) | mem_h 512K | q_E 2M | heads_h 1M
    float*  ctx_E   = (float*)d_ws;
    __half* mem_h   = (__half*)(ctx_E + (size_t)B * E * M);
    float*  q_E     = (float*)(mem_h + (size_t)B * M * E);
    __half* heads_h = (__half*)(q_E + (size_t)B * O * 256);

    prep_kernel<<<544, 256, 0, stream>>>(query, context, memory, W_ch, b_ch,
                                         ctx_E, mem_h, q_E);
    attn_main<<<B * O, 256, 0, stream>>>(ctx_E, mem_h, q_E, w_logit,
                                         b_logit, temp, heads_h);
    post_kernel<<<512, 256, 0, stream>>>(heads_h, W_rh, b_rh, out);
}